// Round 2
// baseline (194.733 us; speedup 1.0000x reference)
//
#include <hip/hip_runtime.h>
#include <hip/hip_bf16.h>
#include <stdint.h>

// Problem: B=8192, E=1024, P=512. x:[8192,2048] f32, w:[1024,512] f32, b:[512] f32.
// out: scalar = mean_i( -S[i,i^4096]/T + log(sum_{j!=i} exp(S[i,j]/T)) ),
// S = zn zn^T (symmetric -> upper triangle of 256x256 blocks), T=0.1.
// Pipeline: prep2 -> gemm1q (fp8 MX, 128^2 R0 structure) -> norm ->
// gemm2 (fp8 MX, 256^2 8-phase m201-style schedule, triangle) -> finalize.
//
// R2: gemm2 ported to the 256^2 8-wave 4-phase-per-K-tile schedule:
// raw s_barrier (no vmcnt drain), stages issued 3+ phases before their
// single per-tile vmcnt(0), setprio around MFMA clusters. gemm1q reverted
// to the R0-proven 2-barrier 128^2 form.
//
// ws layout (bytes):
//   wt8 fp8  [512][1024]    @ 0
//   x8  fp8  [16384][1024]  @ 1048576
//   z   bf16 [16384][512]   @ 17825792
//   zn8 fp8  [8192][1024]   @ 68157440
//   sumexp f32[8192]        @ 84934656
//   pos    f32[8192]        @ 84967424

typedef __attribute__((ext_vector_type(4))) float f32x4;
typedef __attribute__((ext_vector_type(4))) int i32x4;
typedef __attribute__((ext_vector_type(8))) int i32x8;

__device__ __forceinline__ unsigned short f2bf(float f) {
  union { float f; unsigned int u; } v; v.f = f;
  unsigned int u = v.u;
  u += 0x7FFFu + ((u >> 16) & 1u);
  return (unsigned short)(u >> 16);
}

__device__ __forceinline__ float bf2f(unsigned short s) {
  return __uint_as_float(((unsigned int)s) << 16);
}

// ---------------- prep2: x8 = fp8(16*relu(x)); wt8 = fp8(64*w^T); zeros ------
__global__ __launch_bounds__(256) void prep2_kernel(
    const float* __restrict__ x, const float* __restrict__ w,
    unsigned char* __restrict__ x8, unsigned char* __restrict__ wt8,
    float* __restrict__ sumexp, float* __restrict__ out) {
  int tid = blockIdx.x * 256 + threadIdx.x;
  float4 v = ((const float4*)x)[tid];
  int p = __builtin_amdgcn_cvt_pk_fp8_f32(fmaxf(v.x, 0.f) * 16.f,
                                          fmaxf(v.y, 0.f) * 16.f, 0, false);
  p = __builtin_amdgcn_cvt_pk_fp8_f32(fmaxf(v.z, 0.f) * 16.f,
                                      fmaxf(v.w, 0.f) * 16.f, p, true);
  ((int*)x8)[tid] = p;
  if (tid < 512 * 1024) {
    int k = tid & 1023, n = tid >> 10;
    int q = __builtin_amdgcn_cvt_pk_fp8_f32(w[k * 512 + n] * 64.f, 0.f, 0, false);
    wt8[(n << 10) + k] = (unsigned char)(q & 0xFF);
  }
  if (tid < 8192) sumexp[tid] = 0.f;
  if (tid == 0) out[0] = 0.f;
}

// -------- gemm1q: z[16384,512](bf16) = relu(x)@w + b via fp8 MX --------------
// R0-proven: 128x128 tile, BK=128, XOR-swizzled 16 KB LDS/matrix, 2-barrier.
__global__ __launch_bounds__(256) void gemm1q_kernel(
    const unsigned char* __restrict__ x8, const unsigned char* __restrict__ wt8,
    const float* __restrict__ bias, unsigned short* __restrict__ z) {
  __shared__ unsigned char As[16384] __attribute__((aligned(16)));
  __shared__ unsigned char Bs[16384] __attribute__((aligned(16)));
  int b = blockIdx.x;
  int kk = b >> 3;
  int i0 = ((b & 7) * 16 + (kk >> 2)) * 128;
  int n0 = (kk & 3) * 128;

  int tid = threadIdx.x, L = tid & 63, w = tid >> 6;
  int wm = w >> 1, wn = w & 1;
  int l4 = L & 15, q = L >> 4;
  int panel = q * 4096;

  int lp = L ^ ((L >> 3) & 7);
  int srow = w * 32 + (lp >> 1), sh = lp & 1;

  f32x4 acc[4][4];
#pragma unroll
  for (int a = 0; a < 4; ++a)
#pragma unroll
    for (int bq = 0; bq < 4; ++bq) acc[a][bq] = (f32x4)0.f;

  const unsigned char* Ag = x8 + (size_t)(i0 + srow) * 1024 + sh * 16;
  const unsigned char* Bg = wt8 + (size_t)(n0 + srow) * 1024 + sh * 16;

#pragma unroll 1
  for (int k0 = 0; k0 < 1024; k0 += 128) {
    __syncthreads();
#pragma unroll
    for (int t = 0; t < 4; ++t)
      __builtin_amdgcn_global_load_lds(
          (const __attribute__((address_space(1))) void*)(Ag + k0 + t * 32),
          (__attribute__((address_space(3))) void*)(As + t * 4096 + (tid & ~63) * 16),
          16, 0, 0);
#pragma unroll
    for (int t = 0; t < 4; ++t)
      __builtin_amdgcn_global_load_lds(
          (const __attribute__((address_space(1))) void*)(Bg + k0 + t * 32),
          (__attribute__((address_space(3))) void*)(Bs + t * 4096 + (tid & ~63) * 16),
          16, 0, 0);
    __syncthreads();
    i32x8 afr[4];
#pragma unroll
    for (int mt = 0; mt < 4; ++mt) {
      int row = wm * 64 + mt * 16 + l4;
      int p0 = (row * 2) ^ ((row >> 2) & 7);
      i32x4 lo = *(const i32x4*)(As + panel + p0 * 16);
      i32x4 hi = *(const i32x4*)(As + panel + (p0 ^ 1) * 16);
      afr[mt] = (i32x8){lo.x, lo.y, lo.z, lo.w, hi.x, hi.y, hi.z, hi.w};
    }
#pragma unroll
    for (int nt = 0; nt < 4; ++nt) {
      int row = wn * 64 + nt * 16 + l4;
      int p0 = (row * 2) ^ ((row >> 2) & 7);
      i32x4 lo = *(const i32x4*)(Bs + panel + p0 * 16);
      i32x4 hi = *(const i32x4*)(Bs + panel + (p0 ^ 1) * 16);
      i32x8 bfr = (i32x8){lo.x, lo.y, lo.z, lo.w, hi.x, hi.y, hi.z, hi.w};
#pragma unroll
      for (int mt = 0; mt < 4; ++mt)
        acc[mt][nt] = __builtin_amdgcn_mfma_scale_f32_16x16x128_f8f6f4(
            afr[mt], bfr, acc[mt][nt], 0, 0,
            0, 0x7F7F7F7F, 0, 0x7F7F7F7F);
    }
  }

  // epilogue: z = acc/1024 + bias -> bf16
  const float SC = 1.0f / 1024.0f;
#pragma unroll
  for (int nt = 0; nt < 4; ++nt) {
    int n = n0 + wn * 64 + nt * 16 + l4;
    float bn = bias[n];
#pragma unroll
    for (int mt = 0; mt < 4; ++mt) {
      int ib = i0 + wm * 64 + mt * 16 + q * 4;
#pragma unroll
      for (int r = 0; r < 4; ++r)
        z[(size_t)(ib + r) * 512 + n] = f2bf(acc[mt][nt][r] * SC + bn);
    }
  }
}

// -------- norm: zn8 = fp8_e4m3( 16 * z_row / max(||z_row||,eps) ), z bf16 ----
__global__ __launch_bounds__(256) void norm_kernel(
    const unsigned short* __restrict__ z, unsigned char* __restrict__ zn8) {
  int row = blockIdx.x, t = threadIdx.x;
  ushort4 u = ((const ushort4*)z)[row * 256 + t];
  float a0 = bf2f(u.x), a1 = bf2f(u.y), a2 = bf2f(u.z), a3 = bf2f(u.w);
  float ss = a0 * a0 + a1 * a1 + a2 * a2 + a3 * a3;
#pragma unroll
  for (int off = 1; off < 64; off <<= 1) ss += __shfl_xor(ss, off);
  __shared__ float red[4];
  if ((t & 63) == 0) red[t >> 6] = ss;
  __syncthreads();
  float tot = red[0] + red[1] + red[2] + red[3];
  float inv = 16.f / fmaxf(sqrtf(tot), 1e-8f);
  int p = __builtin_amdgcn_cvt_pk_fp8_f32(a0 * inv, a1 * inv, 0, false);
  p = __builtin_amdgcn_cvt_pk_fp8_f32(a2 * inv, a3 * inv, p, true);
  ((int*)zn8)[row * 256 + t] = p;
}

// -------- GEMM2 fp8 symmetric: 256^2 tile, 8 waves, 4-phase/K-tile ----------
// Triangle of 256^2 blocks over 8192 rows: 32*33/2 = 528 blocks, XCD-chunked
// g = (bid&7)*66 + bid>>3 (528 = 8*66, bijective). Per wave: 128x64 output
// (wm in {0,1}, wn in {0..3}), acc[8][4] f32x4. LDS 128 KB: A dbuf 2x32KB,
// B dbuf 2x32KB, XOR panel swizzle (panel = k-quarter, stride 8192).
// Schedule per K-tile (BK=128): 4 phases, each {ds_read subtile + issue
// 1-2 panel stages -> s_barrier -> setprio(1) 8 MFMA setprio(0) -> s_barrier},
// one vmcnt(0) at tile end (stages issued >=3 phases earlier -> no stall).
// A-frag lane L: m=L&15, k=(L>>4)*32+j. C/D: col=L&15, row=(L>>4)*4+reg.
__global__ __launch_bounds__(512) void gemm2_kernel(
    const unsigned char* __restrict__ zn8,
    float* __restrict__ sumexp, float* __restrict__ pos) {
  __shared__ unsigned char smem[131072] __attribute__((aligned(16)));
  // --- triangle decode with XCD chunking ---
  int g = (blockIdx.x & 7) * 66 + (blockIdx.x >> 3);
  int rem = g, bi = 0;
#pragma unroll 1
  while (rem >= 32 - bi) { rem -= 32 - bi; ++bi; }
  int bj = bi + rem;
  bool diag = (bi == bj);
  int i0 = bi * 256, j0 = bj * 256;

  int tid = threadIdx.x, L = tid & 63, w = tid >> 6;
  int wm = w >> 2, wn = w & 3;          // 2 x 4 wave grid
  int l4 = L & 15, q = L >> 4;
  int panel = q * 8192;

  int lp = L ^ ((L >> 3) & 7);
  int srow = w * 32 + (lp >> 1), sh = lp & 1;   // srow in [0,256)
  int ldst = (tid & ~63) * 16;                  // wave-uniform LDS base

  // precomputed swizzled slot byte-offsets (lo half; hi = ^16)
  int pA[8], pB[4];
#pragma unroll
  for (int mt = 0; mt < 8; ++mt) {
    int r = wm * 128 + mt * 16 + l4;
    pA[mt] = ((r * 2) ^ ((r >> 2) & 7)) * 16;
  }
#pragma unroll
  for (int nt = 0; nt < 4; ++nt) {
    int r = wn * 64 + nt * 16 + l4;
    pB[nt] = ((r * 2) ^ ((r >> 2) & 7)) * 16;
  }

  f32x4 acc[8][4];
#pragma unroll
  for (int a = 0; a < 8; ++a)
#pragma unroll
    for (int bq = 0; bq < 4; ++bq) acc[a][bq] = (f32x4)0.f;

  const unsigned char* Ag = zn8 + (size_t)(i0 + srow) * 1024 + sh * 16;
  const unsigned char* Bg = zn8 + (size_t)(j0 + srow) * 1024 + sh * 16;

  // stage one 8 KB panel (512 threads x 16 B) of A or B into buffer nc
  auto stA = [&](int nc, int kk, int t) {
    __builtin_amdgcn_global_load_lds(
        (const __attribute__((address_space(1))) void*)(Ag + kk + t * 32),
        (__attribute__((address_space(3))) void*)(smem + nc * 32768 + t * 8192 + ldst),
        16, 0, 0);
  };
  auto stB = [&](int nc, int kk, int t) {
    __builtin_amdgcn_global_load_lds(
        (const __attribute__((address_space(1))) void*)(Bg + kk + t * 32),
        (__attribute__((address_space(3))) void*)(smem + 65536 + nc * 32768 + t * 8192 + ldst),
        16, 0, 0);
  };

  // prologue: stage K-tile 0 into buf 0, drain, publish
  stA(0, 0, 0); stA(0, 0, 1); stA(0, 0, 2); stA(0, 0, 3);
  if (!diag) { stB(0, 0, 0); stB(0, 0, 1); stB(0, 0, 2); stB(0, 0, 3); }
  asm volatile("s_waitcnt vmcnt(0)" ::: "memory");
  __builtin_amdgcn_s_barrier();
  __builtin_amdgcn_sched_barrier(0);

#pragma unroll 1
  for (int t = 0; t < 8; ++t) {
    int c = t & 1, nc = c ^ 1;
    const unsigned char* Asb = smem + c * 32768;
    const unsigned char* Bsb = diag ? Asb : smem + 65536 + c * 32768;
    int k1 = t * 128 + 128;
    bool st = (t < 7);

    i32x8 afr[4], bf0[2], bf1[2];
    // ---- phase 0: A-half0 + B nt{0,1} reads; stage A panels 0,1 ----
#pragma unroll
    for (int mt = 0; mt < 4; ++mt) {
      i32x4 lo = *(const i32x4*)(Asb + panel + pA[mt]);
      i32x4 hi = *(const i32x4*)(Asb + panel + (pA[mt] ^ 16));
      afr[mt] = (i32x8){lo.x, lo.y, lo.z, lo.w, hi.x, hi.y, hi.z, hi.w};
    }
#pragma unroll
    for (int nt = 0; nt < 2; ++nt) {
      i32x4 lo = *(const i32x4*)(Bsb + panel + pB[nt]);
      i32x4 hi = *(const i32x4*)(Bsb + panel + (pB[nt] ^ 16));
      bf0[nt] = (i32x8){lo.x, lo.y, lo.z, lo.w, hi.x, hi.y, hi.z, hi.w};
    }
    if (st) { stA(nc, k1, 0); stA(nc, k1, 1); }
    __builtin_amdgcn_s_barrier();
    __builtin_amdgcn_sched_barrier(0);
    __builtin_amdgcn_s_setprio(1);
#pragma unroll
    for (int mt = 0; mt < 4; ++mt)
#pragma unroll
      for (int nt = 0; nt < 2; ++nt)
        acc[mt][nt] = __builtin_amdgcn_mfma_scale_f32_16x16x128_f8f6f4(
            afr[mt], bf0[nt], acc[mt][nt], 0, 0, 0, 0x7F7F7F7F, 0, 0x7F7F7F7F);
    __builtin_amdgcn_s_setprio(0);
    __builtin_amdgcn_s_barrier();
    __builtin_amdgcn_sched_barrier(0);

    // ---- phase 1: B nt{2,3} reads; stage A panels 2,3 ----
#pragma unroll
    for (int nt = 0; nt < 2; ++nt) {
      i32x4 lo = *(const i32x4*)(Bsb + panel + pB[2 + nt]);
      i32x4 hi = *(const i32x4*)(Bsb + panel + (pB[2 + nt] ^ 16));
      bf1[nt] = (i32x8){lo.x, lo.y, lo.z, lo.w, hi.x, hi.y, hi.z, hi.w};
    }
    if (st) { stA(nc, k1, 2); stA(nc, k1, 3); }
    __builtin_amdgcn_s_barrier();
    __builtin_amdgcn_sched_barrier(0);
    __builtin_amdgcn_s_setprio(1);
#pragma unroll
    for (int mt = 0; mt < 4; ++mt)
#pragma unroll
      for (int nt = 0; nt < 2; ++nt)
        acc[mt][2 + nt] = __builtin_amdgcn_mfma_scale_f32_16x16x128_f8f6f4(
            afr[mt], bf1[nt], acc[mt][2 + nt], 0, 0, 0, 0x7F7F7F7F, 0, 0x7F7F7F7F);
    __builtin_amdgcn_s_setprio(0);
    __builtin_amdgcn_s_barrier();
    __builtin_amdgcn_sched_barrier(0);

    // ---- phase 2: A-half1 reads; stage B panels 0,1 ----
#pragma unroll
    for (int mt = 0; mt < 4; ++mt) {
      i32x4 lo = *(const i32x4*)(Asb + panel + pA[4 + mt]);
      i32x4 hi = *(const i32x4*)(Asb + panel + (pA[4 + mt] ^ 16));
      afr[mt] = (i32x8){lo.x, lo.y, lo.z, lo.w, hi.x, hi.y, hi.z, hi.w};
    }
    if (st && !diag) { stB(nc, k1, 0); stB(nc, k1, 1); }
    __builtin_amdgcn_s_barrier();
    __builtin_amdgcn_sched_barrier(0);
    __builtin_amdgcn_s_setprio(1);
#pragma unroll
    for (int mt = 0; mt < 4; ++mt)
#pragma unroll
      for (int nt = 0; nt < 2; ++nt)
        acc[4 + mt][2 + nt] = __builtin_amdgcn_mfma_scale_f32_16x16x128_f8f6f4(
            afr[mt], bf1[nt], acc[4 + mt][2 + nt], 0, 0, 0, 0x7F7F7F7F, 0, 0x7F7F7F7F);
    __builtin_amdgcn_s_setprio(0);
    __builtin_amdgcn_s_barrier();
    __builtin_amdgcn_sched_barrier(0);

    // ---- phase 3: stage B panels 2,3; MFMA on held bf0 ----
    if (st && !diag) { stB(nc, k1, 2); stB(nc, k1, 3); }
    __builtin_amdgcn_s_barrier();
    __builtin_amdgcn_sched_barrier(0);
    __builtin_amdgcn_s_setprio(1);
#pragma unroll
    for (int mt = 0; mt < 4; ++mt)
#pragma unroll
      for (int nt = 0; nt < 2; ++nt)
        acc[4 + mt][nt] = __builtin_amdgcn_mfma_scale_f32_16x16x128_f8f6f4(
            afr[mt], bf0[nt], acc[4 + mt][nt], 0, 0, 0, 0x7F7F7F7F, 0, 0x7F7F7F7F);
    __builtin_amdgcn_s_setprio(0);
    asm volatile("s_waitcnt vmcnt(0)" ::: "memory");
    __builtin_amdgcn_s_barrier();
    __builtin_amdgcn_sched_barrier(0);
  }

  // ---- epilogue: s = acc*10/256; diag mask; pos; exp; row/col sums ----
  const float SC = 10.0f / 256.0f;
  float rs[8][4];
  float cs[4] = {0.f, 0.f, 0.f, 0.f};
#pragma unroll
  for (int mt = 0; mt < 8; ++mt)
#pragma unroll
    for (int r = 0; r < 4; ++r) rs[mt][r] = 0.f;
  int ib = i0 + wm * 128 + q * 4;
  int jb = j0 + wn * 64 + l4;
#pragma unroll
  for (int mt = 0; mt < 8; ++mt)
#pragma unroll
    for (int nt = 0; nt < 4; ++nt) {
      int j = jb + nt * 16;
#pragma unroll
      for (int r = 0; r < 4; ++r) {
        int i = ib + mt * 16 + r;
        float s = acc[mt][nt][r] * SC;
        if (j == (i ^ 4096)) { pos[i] = s; pos[j] = s; }
        float e = (i == j) ? 0.f : __expf(s);
        rs[mt][r] += e;
        if (!diag) cs[nt] += e;
      }
    }
  // reduce row-sums across the 16 lanes of each q-group
#pragma unroll
  for (int mt = 0; mt < 8; ++mt)
#pragma unroll
    for (int r = 0; r < 4; ++r) {
      float v = rs[mt][r];
      v += __shfl_xor(v, 1); v += __shfl_xor(v, 2);
      v += __shfl_xor(v, 4); v += __shfl_xor(v, 8);
      rs[mt][r] = v;
    }
  // each lane commits two rows: sel = l4 (mt 0..3) and 16+l4 (mt 4..7)
  float v1 = rs[0][0], v2 = rs[4][0];
#pragma unroll
  for (int mt = 0; mt < 4; ++mt)
#pragma unroll
    for (int r = 0; r < 4; ++r) {
      if (l4 == mt * 4 + r) { v1 = rs[mt][r]; v2 = rs[4 + mt][r]; }
    }
  int rowi = ib + (l4 >> 2) * 16 + (l4 & 3);
  atomicAdd(&sumexp[rowi], v1);
  atomicAdd(&sumexp[rowi + 64], v2);
  if (!diag) {
#pragma unroll
    for (int nt = 0; nt < 4; ++nt) {
      float v = cs[nt];
      v += __shfl_xor(v, 16); v += __shfl_xor(v, 32);
      if (q == 0) atomicAdd(&sumexp[jb + nt * 16], v);
    }
  }
}

// -------- finalize: out += mean-partial(log(sumexp) - pos), 16 blocks --------
__global__ __launch_bounds__(512) void finalize_kernel(
    const float* __restrict__ sumexp, const float* __restrict__ pos,
    float* __restrict__ out) {
  int t = threadIdx.x;
  int i = blockIdx.x * 512 + t;
  float s = logf(sumexp[i]) - pos[i];
#pragma unroll
  for (int off = 1; off < 64; off <<= 1) s += __shfl_xor(s, off);
  __shared__ float red[8];
  if ((t & 63) == 0) red[t >> 6] = s;
  __syncthreads();
  if (t == 0) {
    float tot = 0.f;
    for (int k2 = 0; k2 < 8; ++k2) tot += red[k2];
    atomicAdd(out, tot * (1.0f / 8192.0f));
  }
}

extern "C" void kernel_launch(void* const* d_in, const int* in_sizes, int n_in,
                              void* d_out, int out_size, void* d_ws, size_t ws_size,
                              hipStream_t stream) {
  const float* x = (const float*)d_in[0];
  const float* w = (const float*)d_in[1];
  const float* b = (const float*)d_in[2];
  float* out = (float*)d_out;
  char* ws = (char*)d_ws;
  unsigned char* wt8 = (unsigned char*)(ws);
  unsigned char* x8  = (unsigned char*)(ws + 1048576);
  unsigned short* z  = (unsigned short*)(ws + 17825792);
  unsigned char* zn8 = (unsigned char*)(ws + 68157440);
  float* sumexp      = (float*)(ws + 84934656);
  float* pos         = (float*)(ws + 84967424);

  prep2_kernel<<<16384, 256, 0, stream>>>(x, w, x8, wt8, sumexp, out);
  gemm1q_kernel<<<512, 256, 0, stream>>>(x8, wt8, b, z);
  norm_kernel<<<8192, 256, 0, stream>>>(z, zn8);
  gemm2_kernel<<<528, 512, 0, stream>>>(zn8, sumexp, pos);
  finalize_kernel<<<16, 512, 0, stream>>>(sumexp, pos, out);
}